// Round 13
// baseline (122.330 us; speedup 1.0000x reference)
//
#include <hip/hip_runtime.h>
#include <hip/hip_bf16.h>
#include <stdint.h>

#define S_LEN  2048
#define HIDDEN 2048
#define NH     32
#define NKVH   8
#define HD     64
#define NHD    (NH*HD)    // 2048
#define KVD    (NKVH*HD)  // 512

typedef __attribute__((ext_vector_type(8))) short  short8;
typedef __attribute__((ext_vector_type(4))) short  short4v;
typedef __attribute__((ext_vector_type(4))) float  f32x4;
typedef __attribute__((ext_vector_type(4))) float  float4v;
typedef __attribute__((ext_vector_type(8))) __bf16 bf16x8;

// counted waits + barriers with memory clobber (rule #18 analog).
#define WAITVM8()  asm volatile("s_waitcnt vmcnt(8)" ::: "memory")
#define WAITVM4()  asm volatile("s_waitcnt vmcnt(4)" ::: "memory")
#define WAITVM0()  asm volatile("s_waitcnt vmcnt(0)" ::: "memory")
#define ABARRIER() asm volatile("s_barrier" ::: "memory")

__device__ __forceinline__ short f2bf(float x){
  uint32_t u = __builtin_bit_cast(uint32_t, x);
  u += 0x7fffu + ((u >> 16) & 1u);   // RNE; inputs are finite
  return (short)(u >> 16);
}

__device__ __forceinline__ f32x4 mfma_bf16(short8 a, short8 b, f32x4 c){
  return __builtin_amdgcn_mfma_f32_16x16x32_bf16(
      __builtin_bit_cast(bf16x8, a), __builtin_bit_cast(bf16x8, b), c, 0, 0, 0);
}

// async global->LDS, 16B per lane; LDS dest = wave-uniform base + lane*16
__device__ __forceinline__ void gload16(const short* g, short* l){
  __builtin_amdgcn_global_load_lds(
      (const __attribute__((address_space(1))) void*)g,
      (__attribute__((address_space(3))) void*)l, 16, 0, 0);
}

// ======== pre-pass: hs f32->bf16 + transpose Wq/Wk/Wv (Wo rides in k_gemm_qkv)
__global__ __launch_bounds__(256) void k_prep(const float* __restrict__ hs,
                                              short* __restrict__ hsb,
                                              const float* __restrict__ Wq, short* __restrict__ WqT,
                                              const float* __restrict__ Wk, short* __restrict__ WkT,
                                              const float* __restrict__ Wv, short* __restrict__ WvT){
  int bid = blockIdx.x;
  if (bid < 4096){
    int i = bid*256 + threadIdx.x;
    float4v v = ((const float4v* __restrict__)hs)[i];
    short4v o;
#pragma unroll
    for (int j=0;j<4;j++) o[j] = f2bf(v[j]);
    ((short4v* __restrict__)hsb)[i] = o;
    return;
  }
  bid -= 4096;
  const float* W; short* WT; int R, C, GX;
  if (bid < 4096)      { W = Wq; WT = WqT; R = HIDDEN; C = NHD; GX = 64; }
  else if (bid < 5120) { bid -= 4096; W = Wk; WT = WkT; R = HIDDEN; C = KVD; GX = 16; }
  else                 { bid -= 5120; W = Wv; WT = WvT; R = HIDDEN; C = KVD; GX = 16; }
  const int bx = bid % GX, by = bid / GX;
  __shared__ float tile[32][33];
  const int x = threadIdx.x & 31, y0 = threadIdx.x >> 5;
  const int c0 = bx*32, r0 = by*32;
#pragma unroll
  for (int yy=y0; yy<32; yy+=8) tile[yy][x] = W[(size_t)(r0+yy)*C + c0 + x];
  __syncthreads();
#pragma unroll
  for (int yy=y0; yy<32; yy+=8) WT[(size_t)(c0+yy)*R + r0 + x] = f2bf(tile[x][yy]);
}

// ==== 2-group in-block split-K GEMM cores ======================================
struct GemmIdx {
  int wid, r, g, wr, wc, kg, gtid;
};
__device__ __forceinline__ GemmIdx gemm_idx(){
  GemmIdx ix;
  int tid = threadIdx.x, lane = tid&63;
  ix.kg = tid>>8; ix.gtid = tid&255;
  ix.wid = (tid>>6)&3; ix.r = lane&15; ix.g = lane>>4;
  ix.wr = ix.wid>>1; ix.wc = ix.wid&1;
  return ix;
}

__device__ __forceinline__ void compute128(const short* As, const short* Bs,
                                           f32x4 acc[4][4], const GemmIdx& ix){
  short8 af[4], bf[4];
#pragma unroll
  for (int m=0;m<4;m++) af[m] = *(const short8*)&As[(ix.wr*64 + m*16 + ix.r)*32 + ix.g*8];
#pragma unroll
  for (int n=0;n<4;n++) bf[n] = *(const short8*)&Bs[(ix.wc*64 + n*16 + ix.r)*32 + ix.g*8];
#pragma unroll
  for (int m=0;m<4;m++)
#pragma unroll
    for (int n=0;n<4;n++) acc[m][n] = mfma_bf16(af[m], bf[n], acc[m][n]);
}

__device__ __forceinline__ void red_groups(short* LDS, f32x4 acc[4][4], const GemmIdx& ix){
  __syncthreads();
  float* red = (float*)LDS;
  if (ix.kg){
#pragma unroll
    for (int m=0;m<4;m++)
#pragma unroll
      for (int n=0;n<4;n++)
#pragma unroll
        for (int j=0;j<4;j++)
          red[ix.wid*4096 + (m*16 + ix.g*4 + j)*64 + n*16 + ix.r] = acc[m][n][j];
  }
  __syncthreads();
  if (!ix.kg){
#pragma unroll
    for (int m=0;m<4;m++)
#pragma unroll
      for (int n=0;n<4;n++)
#pragma unroll
        for (int j=0;j<4;j++)
          acc[m][n][j] += red[ix.wid*4096 + (m*16 + ix.g*4 + j)*64 + n*16 + ix.r];
  }
}

// 2-buffer core (64 KB total), plain __syncthreads pipeline (r9-proven config).
template<int NKT>
__device__ __forceinline__ void gemm_core2(const short* __restrict__ A,
                                           const short* __restrict__ BT,
                                           int bm, int bn, short* LDS,
                                           f32x4 acc[4][4], const GemmIdx& ix){
  const int K = HIDDEN;
  const short* gA = A  + (size_t)(bm*128 + (ix.gtid>>2))*K + ix.kg*(NKT*32) + (ix.gtid&3)*8;
  const short* gB = BT + (size_t)(bn*128 + (ix.gtid>>2))*K + ix.kg*(NKT*32) + (ix.gtid&3)*8;
  short* L = LDS + ix.kg*16384;            // 2 bufs * 8192 shorts
  const int w = ix.gtid>>6;

#pragma unroll
  for (int m=0;m<4;m++)
#pragma unroll
    for (int n=0;n<4;n++) acc[m][n] = (f32x4){0.f,0.f,0.f,0.f};

  auto STAGE = [&](int buf, int kt){
    short* As_ = L + buf*8192;             // Bs_ = As_ + 4096
    gload16(gA + kt*32,                As_ + w*512);
    gload16(gA + (size_t)64*K + kt*32, As_ + 2048 + w*512);
    gload16(gB + kt*32,                As_ + 4096 + w*512);
    gload16(gB + (size_t)64*K + kt*32, As_ + 6144 + w*512);
  };

  STAGE(0, 0);
  __syncthreads();                         // buf0 ready
  for (int u=0; u<NKT/2; ++u){
    const int t = 2*u;
    if (t+1 < NKT) STAGE(1, t+1);          // in flight under compute
    compute128(L, L + 4096, acc, ix);
    __syncthreads();                       // buf1 landed; buf0 free
    if (t+2 < NKT) STAGE(0, t+2);
    compute128(L + 8192, L + 12288, acc, ix);
    __syncthreads();
  }
  red_groups(LDS, acc, ix);
}

// 3-buffer core (96 KB): stage-ahead-2, vmcnt(8) — for 1-block/CU kernels (Wo).
template<int NKT>
__device__ __forceinline__ void gemm_core3(const short* __restrict__ A,
                                           const short* __restrict__ BT,
                                           int bm, int bn, short* LDS,
                                           f32x4 acc[4][4], const GemmIdx& ix){
  const int K = HIDDEN;
  const short* gA = A  + (size_t)(bm*128 + (ix.gtid>>2))*K + ix.kg*(NKT*32) + (ix.gtid&3)*8;
  const short* gB = BT + (size_t)(bn*128 + (ix.gtid>>2))*K + ix.kg*(NKT*32) + (ix.gtid&3)*8;
  short* L = LDS + ix.kg*24576;            // 3 bufs * 8192 shorts
  const int w = ix.gtid>>6;

#pragma unroll
  for (int m=0;m<4;m++)
#pragma unroll
    for (int n=0;n<4;n++) acc[m][n] = (f32x4){0.f,0.f,0.f,0.f};

  auto STAGE = [&](int buf, int kt){
    short* As_ = L + buf*8192;
    gload16(gA + kt*32,                As_ + w*512);
    gload16(gA + (size_t)64*K + kt*32, As_ + 2048 + w*512);
    gload16(gB + kt*32,                As_ + 4096 + w*512);
    gload16(gB + (size_t)64*K + kt*32, As_ + 6144 + w*512);
  };

  STAGE(0, 0);
  STAGE(1, 1);
  int cur = 0;
  for (int t=0; t<NKT-2; ++t){
    int nxt = cur+2; if (nxt>=3) nxt-=3;
    STAGE(nxt, t+2);                       // in flight across the barriers
    WAITVM8();                             // oldest 4 (buf cur) retired
    ABARRIER();
    compute128(L + cur*8192, L + cur*8192 + 4096, acc, ix);
    ABARRIER();
    cur = (cur==2) ? 0 : cur+1;
  }
  WAITVM4();                               // t = NKT-2
  ABARRIER();
  compute128(L + cur*8192, L + cur*8192 + 4096, acc, ix);
  ABARRIER();
  cur = (cur==2) ? 0 : cur+1;
  WAITVM0();                               // t = NKT-1 (final drain)
  ABARRIER();
  compute128(L + cur*8192, L + cur*8192 + 4096, acc, ix);

  red_groups(LDS, acc, ix);
}

// QKV GEMM, fused epilogues + Wo-transpose rider region (bn in [24,28)):
//   Q: RoPE + 0.125 scale -> bf16 Qb        (group 0 only)
//   K: RoPE -> bf16 Kb                      (group 0 only)
//   V: LDS round-trip -> coalesced VT[d][s] + VTs[d][s/bs]
//   bn>=24: transpose Wo f32 -> WoT bf16 (pure-BW rider, fills scheduling gaps)
__global__ __launch_bounds__(512, 4) void k_gemm_qkv(const short* __restrict__ hsb,
                                                     const short* __restrict__ WqT,
                                                     const short* __restrict__ WkT,
                                                     const short* __restrict__ WvT,
                                                     const float* __restrict__ cosT,
                                                     const float* __restrict__ sinT,
                                                     const int* __restrict__ nm,
                                                     const float* __restrict__ Wo,
                                                     short* __restrict__ WoT,
                                                     short* __restrict__ Qb,
                                                     short* __restrict__ Kb,
                                                     short* __restrict__ VT,
                                                     short* __restrict__ VTs){
  __shared__ short LDS[32768];             // 64 KB: 2 groups x 2 bufs x 16 KB
  const int bn = blockIdx.x, bm = blockIdx.y;
  GemmIdx ix = gemm_idx();
  f32x4 acc[4][4];

  if (bn < 16){
    gemm_core2<32>(hsb, WqT + (size_t)bn*128*HIDDEN, bm, 0, LDS, acc, ix);
    if (ix.kg) return;
    const int h2 = bn*2 + ix.wc;
#pragma unroll
    for (int m=0;m<4;m++)
#pragma unroll
      for (int j=0;j<4;j++){
        const int s = bm*128 + ix.wr*64 + m*16 + ix.g*4 + j;
        const float* cr = cosT + s*64;
        const float* sr = sinT + s*64;
#pragma unroll
        for (int n=0;n<2;n++){
          const int d = n*16 + ix.r;
          float x1 = acc[m][n][j], x2 = acc[m][n+2][j];
          Qb[(size_t)s*NHD + h2*64 + d]      = f2bf((x1*cr[d]    - x2*sr[d])   *0.125f);
          Qb[(size_t)s*NHD + h2*64 + d + 32] = f2bf((x2*cr[d+32] + x1*sr[d+32])*0.125f);
        }
      }
  } else if (bn < 20){
    gemm_core2<32>(hsb, WkT + (size_t)(bn-16)*128*HIDDEN, bm, 0, LDS, acc, ix);
    if (ix.kg) return;
    const int h2 = (bn-16)*2 + ix.wc;
#pragma unroll
    for (int m=0;m<4;m++)
#pragma unroll
      for (int j=0;j<4;j++){
        const int s = bm*128 + ix.wr*64 + m*16 + ix.g*4 + j;
        const float* cr = cosT + s*64;
        const float* sr = sinT + s*64;
#pragma unroll
        for (int n=0;n<2;n++){
          const int d = n*16 + ix.r;
          float x1 = acc[m][n][j], x2 = acc[m][n+2][j];
          Kb[(size_t)s*KVD + h2*64 + d]      = f2bf(x1*cr[d]    - x2*sr[d]);
          Kb[(size_t)s*KVD + h2*64 + d + 32] = f2bf(x2*cr[d+32] + x1*sr[d+32]);
        }
      }
  } else if (bn < 24){
    gemm_core2<32>(hsb, WvT + (size_t)(bn-20)*128*HIDDEN, bm, 0, LDS, acc, ix);
    // V epilogue via LDS: Vt[128 d][136-stride s] bf16, then coalesced stores.
    const int bs  = nm[0] + 1;                 // power of 2 assumed (nm=3 -> 4)
    const int lbs = 31 - __clz(bs);
    const int d0  = (bn-20)*128;
    const int s0  = bm*128;
    short* Vt = LDS;
    __syncthreads();                           // reduce reads complete
    if (!ix.kg){
#pragma unroll
      for (int n=0;n<4;n++){
        const int dr = ix.wc*64 + n*16 + ix.r;
#pragma unroll
        for (int m=0;m<4;m++){
          const int sc_ = ix.wr*64 + m*16 + ix.g*4;
          short4v o;
#pragma unroll
          for (int j=0;j<4;j++) o[j] = f2bf(acc[m][n][j]);
          *(short4v*)&Vt[dr*136 + sc_] = o;
        }
      }
    }
    __syncthreads();
    const int tid = threadIdx.x;
    // dense VT: 128 rows x 256 B, coalesced short8 stores
#pragma unroll
    for (int it=0; it<4; ++it){
      const int row = tid>>2, c8 = (tid&3)*32 + it*8;
      *(short8*)&VT[(size_t)(d0+row)*S_LEN + s0 + c8] = *(short8*)&Vt[row*136 + c8];
    }
    // sparse VTs: cnt contiguous cols per row
    const int cnt = 128 >> lbs;
    for (int e = tid; e < 128*cnt; e += 512){
      const int row = e >> (7 - lbs), c = e & (cnt - 1);
      VTs[(size_t)(d0+row)*S_LEN + (s0>>lbs) + c] = Vt[row*136 + (c<<lbs)];
    }
  } else {
    // Wo transpose rider: block (bn-24, bm) handles cols [bnt*512,+512) x rows
    // [bm*128,+128) in 64 32x32 tiles; 512 threads process 2 tiles at a time.
    const int bnt = bn - 24;
    float* tf = (float*)LDS;                   // 2 x 32 x 33 floats
    const int tid = threadIdx.x;
    const int half = tid >> 8;
    const int x = tid & 31, y0 = (tid >> 5) & 7;
    const int c0base = bnt*512, r0base = bm*128;
    for (int it=0; it<32; ++it){
      const int t = it*2 + half;               // 0..63
      const int c0 = c0base + (t & 15)*32;
      const int r0 = r0base + (t >> 4)*32;
      __syncthreads();                         // prior writes done before reuse
#pragma unroll
      for (int yy=y0; yy<32; yy+=8)
        tf[half*1056 + yy*33 + x] = Wo[(size_t)(r0+yy)*HIDDEN + c0 + x];
      __syncthreads();
#pragma unroll
      for (int yy=y0; yy<32; yy+=8)
        WoT[(size_t)(c0+yy)*NHD + r0 + x] = f2bf(tf[half*1056 + x*33 + yy]);
    }
  }
}

// Wo GEMM: 2-group split-K, 3-buffer counted-vmcnt pipeline (1 block/CU grid).
__global__ __launch_bounds__(512, 4) void k_gemm(const short* __restrict__ A,
                                                 const short* __restrict__ BT,
                                                 float* __restrict__ C, int Nc){
  __shared__ short LDS[49152];             // 96 KB
  const int bn = blockIdx.x, bm = blockIdx.y;
  GemmIdx ix = gemm_idx();
  f32x4 acc[4][4];
  gemm_core3<32>(A, BT, bm, bn, LDS, acc, ix);
  if (ix.kg) return;
#pragma unroll
  for (int m=0;m<4;m++)
#pragma unroll
    for (int n=0;n<4;n++)
#pragma unroll
      for (int j=0;j<4;j++)
        C[(size_t)(bm*128 + ix.wr*64 + m*16 + ix.g*4 + j)*Nc
          + bn*128 + ix.wc*64 + n*16 + ix.r] = acc[m][n][j];
}

// ======================= attention v5: 1-wave blocks ===========================
// No-max softmax (r12-validated). NEW: row-sum l computed by MFMA with an
// all-ones B fragment — C[q][c] = sum_k P[q][k] lands identically in every
// column, so each lane holds l[j] in-register. Removes the 16-shuffle + adds
// reduce chain per tile (the longest serial VALU section) for +2 MFMA on the
// near-idle matrix pipe. l now sums the bf16-quantized P — exactly consistent
// with the PV numerator.

#define BF16_ONE 16256   // 0x3F80

__device__ __forceinline__ void sm_pv1(f32x4 sc[4],
                                       f32x4& accl,
                                       f32x4 acc[4], short* Pw,
                                       const short* Vtile,   // [d][col], stride S_LEN
                                       int r, int g){
  const short8 ones = {BF16_ONE,BF16_ONE,BF16_ONE,BF16_ONE,
                       BF16_ONE,BF16_ONE,BF16_ONE,BF16_ONE};
  // P = exp(s) -> LDS (C-layout write, A-layout read; same wave: lgkm only)
#pragma unroll
  for (int n=0;n<4;n++)
#pragma unroll
    for (int j=0;j<4;j++)
      Pw[(g*4+j)*72 + n*16 + r] = f2bf(__expf(sc[n][j]));

  short8 pf0 = *(short8*)&Pw[r*72 + g*8];
  short8 pf1 = *(short8*)&Pw[r*72 + 32 + g*8];
  accl = mfma_bf16(pf0, ones, accl);       // l += row-sums (all cols equal)
  accl = mfma_bf16(pf1, ones, accl);
#pragma unroll
  for (int f=0;f<4;f++){
    short8 vf0 = *(const short8*)(Vtile + (size_t)(f*16 + r)*S_LEN + g*8);
    short8 vf1 = *(const short8*)(Vtile + (size_t)(f*16 + r)*S_LEN + 32 + g*8);
    acc[f] = mfma_bf16(pf0, vf0, acc[f]);
    acc[f] = mfma_bf16(pf1, vf1, acc[f]);
  }
}

__global__ __launch_bounds__(64, 4) void k_attn3(const short* __restrict__ Qb,
                                                 const short* __restrict__ Kb,   // [S][KVD]
                                                 const short* __restrict__ VT,   // [KVD][S]
                                                 const short* __restrict__ VTs,  // [KVD][S/bs], stride S
                                                 const int* __restrict__ nm,
                                                 short* __restrict__ Ob){
  const int i  = gridDim.x - 1 - blockIdx.x;   // heavy q-sub-blocks first
  const int qs = i >> 5;                       // 16-row sub-block index, 0..127
  const int h  = i & 31;
  const int hk = h >> 2;
  const int bs = nm[0] + 1;                    // requires bs | 16

  const int lane = threadIdx.x;
  const int r = lane&15, g = lane>>4;

  __shared__ short Pw[16*72];

  const int qlo = qs*16;

  short8 qf0 = *(const short8*)(Qb + (size_t)(qlo + r)*NHD + h*HD + g*8);
  short8 qf1 = *(const short8*)(Qb + (size_t)(qlo + r)*NHD + h*HD + 32 + g*8);

  f32x4 acc[4];
  f32x4 accl = (f32x4){0.f,0.f,0.f,0.f};
#pragma unroll
  for (int f=0;f<4;f++) acc[f] = (f32x4){0.f,0.f,0.f,0.f};

  const short* Kg  = Kb  + hk*HD;
  const short* Vsg = VTs + (size_t)hk*HD*S_LEN;
  const short* Vdg = VT  + (size_t)hk*HD*S_LEN;

  // ---- column pass: keys k = bs*c for c < cmax (all causally allowed) ----
  const int cmax = qlo / bs;                   // exact (bs | 16)
  const int nct = (cmax + 63) >> 6;
  for (int ct=0; ct<nct; ++ct){
    const int cbase = ct*64;
    f32x4 sc[4];
#pragma unroll
    for (int n=0;n<4;n++){
      const int key = bs*(cbase + n*16 + r);
      short8 kf0 = *(const short8*)(Kg + (size_t)key*KVD + g*8);
      short8 kf1 = *(const short8*)(Kg + (size_t)key*KVD + 32 + g*8);
      f32x4 z = (f32x4){0.f,0.f,0.f,0.f};
      z = mfma_bf16(qf0, kf0, z);
      sc[n] = mfma_bf16(qf1, kf1, z);
    }
    if (cmax - cbase < 64){                    // partial last tile only
#pragma unroll
      for (int n=0;n<4;n++){
        if (cbase + n*16 + r >= cmax){
#pragma unroll
          for (int j=0;j<4;j++) sc[n][j] = -1e30f;
        }
      }
    }
    sm_pv1(sc, accl, acc, Pw, Vsg + cbase, r, g);
  }

  // ---- diag: the 16 keys [qlo, qlo+16) with the full mask ----
  {
    const short8 ones = {BF16_ONE,BF16_ONE,BF16_ONE,BF16_ONE,
                         BF16_ONE,BF16_ONE,BF16_ONE,BF16_ONE};
    const int key = qlo + r;                   // one 16-key fragment
    short8 kf0 = *(const short8*)(Kg + (size_t)key*KVD + g*8);
    short8 kf1 = *(const short8*)(Kg + (size_t)key*KVD + 32 + g*8);
    f32x4 z = (f32x4){0.f,0.f,0.f,0.f};
    z = mfma_bf16(qf0, kf0, z);
    f32x4 sc0 = mfma_bf16(qf1, kf1, z);

    const int rb = r / bs, rm = r % bs;
#pragma unroll
    for (int j=0;j<4;j++){
      const int qrel = g*4 + j;
      bool ok = (r <= qrel) && ((rm == 0) || (rb == qrel/bs));
      sc0[j] = ok ? sc0[j] : -1e30f;
    }

#pragma unroll
    for (int j=0;j<4;j++){
      Pw[(g*4+j)*72 + r]      = f2bf(__expf(sc0[j]));
      Pw[(g*4+j)*72 + 16 + r] = 0;
    }
    short8 pf0 = *(short8*)&Pw[r*72 + g*8];    // cols 0..31 (16..31 zero)
    accl = mfma_bf16(pf0, ones, accl);
#pragma unroll
    for (int f=0;f<4;f++){
      short8 vf0 = *(const short8*)(Vdg + (size_t)(f*16 + r)*S_LEN + qlo + g*8);
      acc[f] = mfma_bf16(pf0, vf0, acc[f]);
    }
  }

  // epilogue: O /= l, write bf16 (rows qlo + g*4 + j)
#pragma unroll
  for (int j=0;j<4;j++){
    float inv = 1.f / accl[j];
    const int q = qlo + g*4 + j;
#pragma unroll
    for (int f=0;f<4;f++)
      Ob[(size_t)q*NHD + h*HD + f*16 + r] = f2bf(acc[f][j]*inv);
  }
}

// ---------------- launch ----------------
extern "C" void kernel_launch(void* const* d_in, const int* in_sizes, int n_in,
                              void* d_out, int out_size, void* d_ws, size_t ws_size,
                              hipStream_t stream){
  const float* hs   = (const float*)d_in[0];
  const float* cosT = (const float*)d_in[1];
  const float* sinT = (const float*)d_in[2];
  const float* Wq   = (const float*)d_in[3];
  const float* Wk   = (const float*)d_in[4];
  const float* Wv   = (const float*)d_in[5];
  const float* Wo   = (const float*)d_in[6];
  const int*   nm   = (const int*)d_in[7];

  char* ws = (char*)d_ws;
  short* hsb  = (short*)(ws);                   // 8 MB
  short* WqT  = (short*)(ws + (8ull<<20));      // 8 MB
  short* WkT  = (short*)(ws + (16ull<<20));     // 2 MB
  short* WvT  = (short*)(ws + (18ull<<20));     // 2 MB
  short* WoT  = (short*)(ws + (20ull<<20));     // 8 MB
  short* Qb   = (short*)(ws + (28ull<<20));     // 8 MB
  short* Kb   = (short*)(ws + (36ull<<20));     // 2 MB
  short* VT   = (short*)(ws + (38ull<<20));     // 2 MB
  short* VTs  = (short*)(ws + (40ull<<20));     // 2 MB
  short* attnb= (short*)(ws + (42ull<<20));     // 8 MB
  float* out  = (float*)d_out;

  // pre-pass (hs cast + Wq/Wk/Wv transposes; Wo transpose rides in k_gemm_qkv)
  k_prep<<<dim3(10240), 256, 0, stream>>>(hs, hsb, Wq, WqT, Wk, WkT, Wv, WvT);

  // QKV GEMM (2-buf, 64 KB) + fused epilogues + Wo-transpose rider blocks
  k_gemm_qkv<<<dim3(28, 16), 512, 0, stream>>>(hsb, WqT, WkT, WvT, cosT, sinT, nm,
                                               Wo, WoT, Qb, Kb, VT, VTs);

  k_attn3<<<dim3((S_LEN/16)*NH), 64, 0, stream>>>(Qb, Kb, VT, VTs, nm, attnb);

  // Wo GEMM (3-buf counted-vmcnt pipeline, 96 KB — grid is 1 block/CU)
  k_gemm<<<dim3(NHD/128, S_LEN/128), 512, 0, stream>>>(attnb, WoT, out, HIDDEN);
}

// Round 14
// 122.306 us; speedup vs baseline: 1.0002x; 1.0002x over previous
//
#include <hip/hip_runtime.h>
#include <hip/hip_bf16.h>
#include <stdint.h>

#define S_LEN  2048
#define HIDDEN 2048
#define NH     32
#define NKVH   8
#define HD     64
#define NHD    (NH*HD)    // 2048
#define KVD    (NKVH*HD)  // 512

typedef __attribute__((ext_vector_type(8))) short  short8;
typedef __attribute__((ext_vector_type(4))) short  short4v;
typedef __attribute__((ext_vector_type(4))) float  f32x4;
typedef __attribute__((ext_vector_type(4))) float  float4v;
typedef __attribute__((ext_vector_type(8))) __bf16 bf16x8;

// counted waits + barriers with memory clobber (rule #18 analog).
#define WAITVM8()  asm volatile("s_waitcnt vmcnt(8)" ::: "memory")
#define WAITVM4()  asm volatile("s_waitcnt vmcnt(4)" ::: "memory")
#define WAITVM0()  asm volatile("s_waitcnt vmcnt(0)" ::: "memory")
#define ABARRIER() asm volatile("s_barrier" ::: "memory")

__device__ __forceinline__ short f2bf(float x){
  uint32_t u = __builtin_bit_cast(uint32_t, x);
  u += 0x7fffu + ((u >> 16) & 1u);   // RNE; inputs are finite
  return (short)(u >> 16);
}

__device__ __forceinline__ f32x4 mfma_bf16(short8 a, short8 b, f32x4 c){
  return __builtin_amdgcn_mfma_f32_16x16x32_bf16(
      __builtin_bit_cast(bf16x8, a), __builtin_bit_cast(bf16x8, b), c, 0, 0, 0);
}

// async global->LDS, 16B per lane; LDS dest = wave-uniform base + lane*16
__device__ __forceinline__ void gload16(const short* g, short* l){
  __builtin_amdgcn_global_load_lds(
      (const __attribute__((address_space(1))) void*)g,
      (__attribute__((address_space(3))) void*)l, 16, 0, 0);
}

// ======== pre-pass: hs f32->bf16 + transpose Wq/Wk/Wv (Wo rides in k_gemm_qkv)
__global__ __launch_bounds__(256) void k_prep(const float* __restrict__ hs,
                                              short* __restrict__ hsb,
                                              const float* __restrict__ Wq, short* __restrict__ WqT,
                                              const float* __restrict__ Wk, short* __restrict__ WkT,
                                              const float* __restrict__ Wv, short* __restrict__ WvT){
  int bid = blockIdx.x;
  if (bid < 4096){
    int i = bid*256 + threadIdx.x;
    float4v v = ((const float4v* __restrict__)hs)[i];
    short4v o;
#pragma unroll
    for (int j=0;j<4;j++) o[j] = f2bf(v[j]);
    ((short4v* __restrict__)hsb)[i] = o;
    return;
  }
  bid -= 4096;
  const float* W; short* WT; int R, C, GX;
  if (bid < 4096)      { W = Wq; WT = WqT; R = HIDDEN; C = NHD; GX = 64; }
  else if (bid < 5120) { bid -= 4096; W = Wk; WT = WkT; R = HIDDEN; C = KVD; GX = 16; }
  else                 { bid -= 5120; W = Wv; WT = WvT; R = HIDDEN; C = KVD; GX = 16; }
  const int bx = bid % GX, by = bid / GX;
  __shared__ float tile[32][33];
  const int x = threadIdx.x & 31, y0 = threadIdx.x >> 5;
  const int c0 = bx*32, r0 = by*32;
#pragma unroll
  for (int yy=y0; yy<32; yy+=8) tile[yy][x] = W[(size_t)(r0+yy)*C + c0 + x];
  __syncthreads();
#pragma unroll
  for (int yy=y0; yy<32; yy+=8) WT[(size_t)(c0+yy)*R + r0 + x] = f2bf(tile[x][yy]);
}

// ==== 2-group in-block split-K GEMM cores ======================================
// LDS tile image is XOR-swizzled to kill ds_read_b128 bank conflicts:
//   elem(row,col) stored at short-offset (row*32+col) ^ ((row&7)<<3)
// gload_lds writes linear slots (rule #21), so the SOURCE address per lane is
// pre-swizzled via the inverse map (constants folded into gA/gB); reads XOR a
// per-lane constant sx = (r&7)<<3. Zero extra instructions in the K-loop.
struct GemmIdx {
  int wid, r, g, wr, wc, kg, gtid, srow, c8, sx;
};
__device__ __forceinline__ GemmIdx gemm_idx(){
  GemmIdx ix;
  int tid = threadIdx.x, lane = tid&63;
  ix.kg = tid>>8; ix.gtid = tid&255;
  ix.wid = (tid>>6)&3; ix.r = lane&15; ix.g = lane>>4;
  ix.wr = ix.wid>>1; ix.wc = ix.wid&1;
  // inverse swizzle for linear stage slot o = gtid*8 (verified bijective):
  const int gt = ix.gtid;
  const int row0 = ((gt>>2) ^ (gt>>4)) & 1;
  ix.srow = (((gt>>3)<<1) | row0);                         // 0..63 (call adds +64)
  ix.c8   = ((gt ^ (gt>>2) ^ (gt>>4)) & 1) | ((((gt>>1) ^ (gt>>3)) & 1) << 1);
  ix.sx   = (ix.r & 7) << 3;                               // read-side XOR
  return ix;
}

__device__ __forceinline__ void compute128(const short* As, const short* Bs,
                                           f32x4 acc[4][4], const GemmIdx& ix){
  short8 af[4], bf[4];
#pragma unroll
  for (int m=0;m<4;m++)
    af[m] = *(const short8*)&As[((ix.wr*64 + m*16 + ix.r)*32 + ix.g*8) ^ ix.sx];
#pragma unroll
  for (int n=0;n<4;n++)
    bf[n] = *(const short8*)&Bs[((ix.wc*64 + n*16 + ix.r)*32 + ix.g*8) ^ ix.sx];
#pragma unroll
  for (int m=0;m<4;m++)
#pragma unroll
    for (int n=0;n<4;n++) acc[m][n] = mfma_bf16(af[m], bf[n], acc[m][n]);
}

__device__ __forceinline__ void red_groups(short* LDS, f32x4 acc[4][4], const GemmIdx& ix){
  __syncthreads();
  float* red = (float*)LDS;
  if (ix.kg){
#pragma unroll
    for (int m=0;m<4;m++)
#pragma unroll
      for (int n=0;n<4;n++)
#pragma unroll
        for (int j=0;j<4;j++)
          red[ix.wid*4096 + (m*16 + ix.g*4 + j)*64 + n*16 + ix.r] = acc[m][n][j];
  }
  __syncthreads();
  if (!ix.kg){
#pragma unroll
    for (int m=0;m<4;m++)
#pragma unroll
      for (int n=0;n<4;n++)
#pragma unroll
        for (int j=0;j<4;j++)
          acc[m][n][j] += red[ix.wid*4096 + (m*16 + ix.g*4 + j)*64 + n*16 + ix.r];
  }
}

// 2-buffer core (64 KB total), plain __syncthreads pipeline (r9-proven config).
template<int NKT>
__device__ __forceinline__ void gemm_core2(const short* __restrict__ A,
                                           const short* __restrict__ BT,
                                           int bm, int bn, short* LDS,
                                           f32x4 acc[4][4], const GemmIdx& ix){
  const int K = HIDDEN;
  const short* gA = A  + (size_t)(bm*128 + ix.srow)*K + ix.kg*(NKT*32) + ix.c8*8;
  const short* gB = BT + (size_t)(bn*128 + ix.srow)*K + ix.kg*(NKT*32) + ix.c8*8;
  short* L = LDS + ix.kg*16384;            // 2 bufs * 8192 shorts
  const int w = ix.gtid>>6;

#pragma unroll
  for (int m=0;m<4;m++)
#pragma unroll
    for (int n=0;n<4;n++) acc[m][n] = (f32x4){0.f,0.f,0.f,0.f};

  auto STAGE = [&](int buf, int kt){
    short* As_ = L + buf*8192;             // Bs_ = As_ + 4096
    gload16(gA + kt*32,                As_ + w*512);
    gload16(gA + (size_t)64*K + kt*32, As_ + 2048 + w*512);
    gload16(gB + kt*32,                As_ + 4096 + w*512);
    gload16(gB + (size_t)64*K + kt*32, As_ + 6144 + w*512);
  };

  STAGE(0, 0);
  __syncthreads();                         // buf0 ready
  for (int u=0; u<NKT/2; ++u){
    const int t = 2*u;
    if (t+1 < NKT) STAGE(1, t+1);          // in flight under compute
    compute128(L, L + 4096, acc, ix);
    __syncthreads();                       // buf1 landed; buf0 free
    if (t+2 < NKT) STAGE(0, t+2);
    compute128(L + 8192, L + 12288, acc, ix);
    __syncthreads();
  }
  red_groups(LDS, acc, ix);
}

// 3-buffer core (96 KB): stage-ahead-2, vmcnt(8) — for 1-block/CU kernels (Wo).
template<int NKT>
__device__ __forceinline__ void gemm_core3(const short* __restrict__ A,
                                           const short* __restrict__ BT,
                                           int bm, int bn, short* LDS,
                                           f32x4 acc[4][4], const GemmIdx& ix){
  const int K = HIDDEN;
  const short* gA = A  + (size_t)(bm*128 + ix.srow)*K + ix.kg*(NKT*32) + ix.c8*8;
  const short* gB = BT + (size_t)(bn*128 + ix.srow)*K + ix.kg*(NKT*32) + ix.c8*8;
  short* L = LDS + ix.kg*24576;            // 3 bufs * 8192 shorts
  const int w = ix.gtid>>6;

#pragma unroll
  for (int m=0;m<4;m++)
#pragma unroll
    for (int n=0;n<4;n++) acc[m][n] = (f32x4){0.f,0.f,0.f,0.f};

  auto STAGE = [&](int buf, int kt){
    short* As_ = L + buf*8192;
    gload16(gA + kt*32,                As_ + w*512);
    gload16(gA + (size_t)64*K + kt*32, As_ + 2048 + w*512);
    gload16(gB + kt*32,                As_ + 4096 + w*512);
    gload16(gB + (size_t)64*K + kt*32, As_ + 6144 + w*512);
  };

  STAGE(0, 0);
  STAGE(1, 1);
  int cur = 0;
  for (int t=0; t<NKT-2; ++t){
    int nxt = cur+2; if (nxt>=3) nxt-=3;
    STAGE(nxt, t+2);                       // in flight across the barriers
    WAITVM8();                             // oldest 4 (buf cur) retired
    ABARRIER();
    compute128(L + cur*8192, L + cur*8192 + 4096, acc, ix);
    ABARRIER();
    cur = (cur==2) ? 0 : cur+1;
  }
  WAITVM4();                               // t = NKT-2
  ABARRIER();
  compute128(L + cur*8192, L + cur*8192 + 4096, acc, ix);
  ABARRIER();
  cur = (cur==2) ? 0 : cur+1;
  WAITVM0();                               // t = NKT-1 (final drain)
  ABARRIER();
  compute128(L + cur*8192, L + cur*8192 + 4096, acc, ix);

  red_groups(LDS, acc, ix);
}

// QKV GEMM, fused epilogues + Wo-transpose rider region (bn in [24,28)):
//   Q: RoPE + 0.125 scale -> bf16 Qb        (group 0 only)
//   K: RoPE -> bf16 Kb                      (group 0 only)
//   V: LDS round-trip -> coalesced VT[d][s] + VTs[d][s/bs]
//   bn>=24: transpose Wo f32 -> WoT bf16 (pure-BW rider, fills scheduling gaps)
__global__ __launch_bounds__(512, 4) void k_gemm_qkv(const short* __restrict__ hsb,
                                                     const short* __restrict__ WqT,
                                                     const short* __restrict__ WkT,
                                                     const short* __restrict__ WvT,
                                                     const float* __restrict__ cosT,
                                                     const float* __restrict__ sinT,
                                                     const int* __restrict__ nm,
                                                     const float* __restrict__ Wo,
                                                     short* __restrict__ WoT,
                                                     short* __restrict__ Qb,
                                                     short* __restrict__ Kb,
                                                     short* __restrict__ VT,
                                                     short* __restrict__ VTs){
  __shared__ short LDS[32768];             // 64 KB: 2 groups x 2 bufs x 16 KB
  const int bn = blockIdx.x, bm = blockIdx.y;
  GemmIdx ix = gemm_idx();
  f32x4 acc[4][4];

  if (bn < 16){
    gemm_core2<32>(hsb, WqT + (size_t)bn*128*HIDDEN, bm, 0, LDS, acc, ix);
    if (ix.kg) return;
    const int h2 = bn*2 + ix.wc;
#pragma unroll
    for (int m=0;m<4;m++)
#pragma unroll
      for (int j=0;j<4;j++){
        const int s = bm*128 + ix.wr*64 + m*16 + ix.g*4 + j;
        const float* cr = cosT + s*64;
        const float* sr = sinT + s*64;
#pragma unroll
        for (int n=0;n<2;n++){
          const int d = n*16 + ix.r;
          float x1 = acc[m][n][j], x2 = acc[m][n+2][j];
          Qb[(size_t)s*NHD + h2*64 + d]      = f2bf((x1*cr[d]    - x2*sr[d])   *0.125f);
          Qb[(size_t)s*NHD + h2*64 + d + 32] = f2bf((x2*cr[d+32] + x1*sr[d+32])*0.125f);
        }
      }
  } else if (bn < 20){
    gemm_core2<32>(hsb, WkT + (size_t)(bn-16)*128*HIDDEN, bm, 0, LDS, acc, ix);
    if (ix.kg) return;
    const int h2 = (bn-16)*2 + ix.wc;
#pragma unroll
    for (int m=0;m<4;m++)
#pragma unroll
      for (int j=0;j<4;j++){
        const int s = bm*128 + ix.wr*64 + m*16 + ix.g*4 + j;
        const float* cr = cosT + s*64;
        const float* sr = sinT + s*64;
#pragma unroll
        for (int n=0;n<2;n++){
          const int d = n*16 + ix.r;
          float x1 = acc[m][n][j], x2 = acc[m][n+2][j];
          Kb[(size_t)s*KVD + h2*64 + d]      = f2bf(x1*cr[d]    - x2*sr[d]);
          Kb[(size_t)s*KVD + h2*64 + d + 32] = f2bf(x2*cr[d+32] + x1*sr[d+32]);
        }
      }
  } else if (bn < 24){
    gemm_core2<32>(hsb, WvT + (size_t)(bn-20)*128*HIDDEN, bm, 0, LDS, acc, ix);
    // V epilogue via LDS: Vt[128 d][136-stride s] bf16, then coalesced stores.
    const int bs  = nm[0] + 1;                 // power of 2 assumed (nm=3 -> 4)
    const int lbs = 31 - __clz(bs);
    const int d0  = (bn-20)*128;
    const int s0  = bm*128;
    short* Vt = LDS;
    __syncthreads();                           // reduce reads complete
    if (!ix.kg){
#pragma unroll
      for (int n=0;n<4;n++){
        const int dr = ix.wc*64 + n*16 + ix.r;
#pragma unroll
        for (int m=0;m<4;m++){
          const int sc_ = ix.wr*64 + m*16 + ix.g*4;
          short4v o;
#pragma unroll
          for (int j=0;j<4;j++) o[j] = f2bf(acc[m][n][j]);
          *(short4v*)&Vt[dr*136 + sc_] = o;
        }
      }
    }
    __syncthreads();
    const int tid = threadIdx.x;
    // dense VT: 128 rows x 256 B, coalesced short8 stores
#pragma unroll
    for (int it=0; it<4; ++it){
      const int row = tid>>2, c8 = (tid&3)*32 + it*8;
      *(short8*)&VT[(size_t)(d0+row)*S_LEN + s0 + c8] = *(short8*)&Vt[row*136 + c8];
    }
    // sparse VTs: cnt contiguous cols per row
    const int cnt = 128 >> lbs;
    for (int e = tid; e < 128*cnt; e += 512){
      const int row = e >> (7 - lbs), c = e & (cnt - 1);
      VTs[(size_t)(d0+row)*S_LEN + (s0>>lbs) + c] = Vt[row*136 + (c<<lbs)];
    }
  } else {
    // Wo transpose rider: block (bn-24, bm) handles cols [bnt*512,+512) x rows
    // [bm*128,+128) in 64 32x32 tiles; 512 threads process 2 tiles at a time.
    const int bnt = bn - 24;
    float* tf = (float*)LDS;                   // 2 x 32 x 33 floats
    const int tid = threadIdx.x;
    const int half = tid >> 8;
    const int x = tid & 31, y0 = (tid >> 5) & 7;
    const int c0base = bnt*512, r0base = bm*128;
    for (int it=0; it<32; ++it){
      const int t = it*2 + half;               // 0..63
      const int c0 = c0base + (t & 15)*32;
      const int r0 = r0base + (t >> 4)*32;
      __syncthreads();                         // prior writes done before reuse
#pragma unroll
      for (int yy=y0; yy<32; yy+=8)
        tf[half*1056 + yy*33 + x] = Wo[(size_t)(r0+yy)*HIDDEN + c0 + x];
      __syncthreads();
#pragma unroll
      for (int yy=y0; yy<32; yy+=8)
        WoT[(size_t)(c0+yy)*NHD + r0 + x] = f2bf(tf[half*1056 + x*33 + yy]);
    }
  }
}

// Wo GEMM: 2-group split-K, 3-buffer counted-vmcnt pipeline (1 block/CU grid).
__global__ __launch_bounds__(512, 4) void k_gemm(const short* __restrict__ A,
                                                 const short* __restrict__ BT,
                                                 float* __restrict__ C, int Nc){
  __shared__ short LDS[49152];             // 96 KB
  const int bn = blockIdx.x, bm = blockIdx.y;
  GemmIdx ix = gemm_idx();
  f32x4 acc[4][4];
  gemm_core3<32>(A, BT, bm, bn, LDS, acc, ix);
  if (ix.kg) return;
#pragma unroll
  for (int m=0;m<4;m++)
#pragma unroll
    for (int n=0;n<4;n++)
#pragma unroll
      for (int j=0;j<4;j++)
        C[(size_t)(bm*128 + ix.wr*64 + m*16 + ix.g*4 + j)*Nc
          + bn*128 + ix.wc*64 + n*16 + ix.r] = acc[m][n][j];
}

// ======================= attention v5: 1-wave blocks ===========================
// No-max softmax (r12-validated); row-sum l via MFMA ones-fragment (r13).

#define BF16_ONE 16256   // 0x3F80

__device__ __forceinline__ void sm_pv1(f32x4 sc[4],
                                       f32x4& accl,
                                       f32x4 acc[4], short* Pw,
                                       const short* Vtile,   // [d][col], stride S_LEN
                                       int r, int g){
  const short8 ones = {BF16_ONE,BF16_ONE,BF16_ONE,BF16_ONE,
                       BF16_ONE,BF16_ONE,BF16_ONE,BF16_ONE};
  // P = exp(s) -> LDS (C-layout write, A-layout read; same wave: lgkm only)
#pragma unroll
  for (int n=0;n<4;n++)
#pragma unroll
    for (int j=0;j<4;j++)
      Pw[(g*4+j)*72 + n*16 + r] = f2bf(__expf(sc[n][j]));

  short8 pf0 = *(short8*)&Pw[r*72 + g*8];
  short8 pf1 = *(short8*)&Pw[r*72 + 32 + g*8];
  accl = mfma_bf16(pf0, ones, accl);       // l += row-sums (all cols equal)
  accl = mfma_bf16(pf1, ones, accl);
#pragma unroll
  for (int f=0;f<4;f++){
    short8 vf0 = *(const short8*)(Vtile + (size_t)(f*16 + r)*S_LEN + g*8);
    short8 vf1 = *(const short8*)(Vtile + (size_t)(f*16 + r)*S_LEN + 32 + g*8);
    acc[f] = mfma_bf16(pf0, vf0, acc[f]);
    acc[f] = mfma_bf16(pf1, vf1, acc[f]);
  }
}

__global__ __launch_bounds__(64, 4) void k_attn3(const short* __restrict__ Qb,
                                                 const short* __restrict__ Kb,   // [S][KVD]
                                                 const short* __restrict__ VT,   // [KVD][S]
                                                 const short* __restrict__ VTs,  // [KVD][S/bs], stride S
                                                 const int* __restrict__ nm,
                                                 short* __restrict__ Ob){
  const int i  = gridDim.x - 1 - blockIdx.x;   // heavy q-sub-blocks first
  const int qs = i >> 5;                       // 16-row sub-block index, 0..127
  const int h  = i & 31;
  const int hk = h >> 2;
  const int bs = nm[0] + 1;                    // requires bs | 16

  const int lane = threadIdx.x;
  const int r = lane&15, g = lane>>4;

  __shared__ short Pw[16*72];

  const int qlo = qs*16;

  short8 qf0 = *(const short8*)(Qb + (size_t)(qlo + r)*NHD + h*HD + g*8);
  short8 qf1 = *(const short8*)(Qb + (size_t)(qlo + r)*NHD + h*HD + 32 + g*8);

  f32x4 acc[4];
  f32x4 accl = (f32x4){0.f,0.f,0.f,0.f};
#pragma unroll
  for (int f=0;f<4;f++) acc[f] = (f32x4){0.f,0.f,0.f,0.f};

  const short* Kg  = Kb  + hk*HD;
  const short* Vsg = VTs + (size_t)hk*HD*S_LEN;
  const short* Vdg = VT  + (size_t)hk*HD*S_LEN;

  // ---- column pass: keys k = bs*c for c < cmax (all causally allowed) ----
  const int cmax = qlo / bs;                   // exact (bs | 16)
  const int nct = (cmax + 63) >> 6;
  for (int ct=0; ct<nct; ++ct){
    const int cbase = ct*64;
    f32x4 sc[4];
#pragma unroll
    for (int n=0;n<4;n++){
      const int key = bs*(cbase + n*16 + r);
      short8 kf0 = *(const short8*)(Kg + (size_t)key*KVD + g*8);
      short8 kf1 = *(const short8*)(Kg + (size_t)key*KVD + 32 + g*8);
      f32x4 z = (f32x4){0.f,0.f,0.f,0.f};
      z = mfma_bf16(qf0, kf0, z);
      sc[n] = mfma_bf16(qf1, kf1, z);
    }
    if (cmax - cbase < 64){                    // partial last tile only
#pragma unroll
      for (int n=0;n<4;n++){
        if (cbase + n*16 + r >= cmax){
#pragma unroll
          for (int j=0;j<4;j++) sc[n][j] = -1e30f;
        }
      }
    }
    sm_pv1(sc, accl, acc, Pw, Vsg + cbase, r, g);
  }

  // ---- diag: the 16 keys [qlo, qlo+16) with the full mask ----
  {
    const short8 ones = {BF16_ONE,BF16_ONE,BF16_ONE,BF16_ONE,
                         BF16_ONE,BF16_ONE,BF16_ONE,BF16_ONE};
    const int key = qlo + r;                   // one 16-key fragment
    short8 kf0 = *(const short8*)(Kg + (size_t)key*KVD + g*8);
    short8 kf1 = *(const short8*)(Kg + (size_t)key*KVD + 32 + g*8);
    f32x4 z = (f32x4){0.f,0.f,0.f,0.f};
    z = mfma_bf16(qf0, kf0, z);
    f32x4 sc0 = mfma_bf16(qf1, kf1, z);

    const int rb = r / bs, rm = r % bs;
#pragma unroll
    for (int j=0;j<4;j++){
      const int qrel = g*4 + j;
      bool ok = (r <= qrel) && ((rm == 0) || (rb == qrel/bs));
      sc0[j] = ok ? sc0[j] : -1e30f;
    }

#pragma unroll
    for (int j=0;j<4;j++){
      Pw[(g*4+j)*72 + r]      = f2bf(__expf(sc0[j]));
      Pw[(g*4+j)*72 + 16 + r] = 0;
    }
    short8 pf0 = *(short8*)&Pw[r*72 + g*8];    // cols 0..31 (16..31 zero)
    accl = mfma_bf16(pf0, ones, accl);
#pragma unroll
    for (int f=0;f<4;f++){
      short8 vf0 = *(const short8*)(Vdg + (size_t)(f*16 + r)*S_LEN + qlo + g*8);
      acc[f] = mfma_bf16(pf0, vf0, acc[f]);
    }
  }

  // epilogue: O /= l, write bf16 (rows qlo + g*4 + j)
#pragma unroll
  for (int j=0;j<4;j++){
    float inv = 1.f / accl[j];
    const int q = qlo + g*4 + j;
#pragma unroll
    for (int f=0;f<4;f++)
      Ob[(size_t)q*NHD + h*HD + f*16 + r] = f2bf(acc[f][j]*inv);
  }
}

// ---------------- launch ----------------
extern "C" void kernel_launch(void* const* d_in, const int* in_sizes, int n_in,
                              void* d_out, int out_size, void* d_ws, size_t ws_size,
                              hipStream_t stream){
  const float* hs   = (const float*)d_in[0];
  const float* cosT = (const float*)d_in[1];
  const float* sinT = (const float*)d_in[2];
  const float* Wq   = (const float*)d_in[3];
  const float* Wk   = (const float*)d_in[4];
  const float* Wv   = (const float*)d_in[5];
  const float* Wo   = (const float*)d_in[6];
  const int*   nm   = (const int*)d_in[7];

  char* ws = (char*)d_ws;
  short* hsb  = (short*)(ws);                   // 8 MB
  short* WqT  = (short*)(ws + (8ull<<20));      // 8 MB
  short* WkT  = (short*)(ws + (16ull<<20));     // 2 MB
  short* WvT  = (short*)(ws + (18ull<<20));     // 2 MB
  short* WoT  = (short*)(ws + (20ull<<20));     // 8 MB
  short* Qb   = (short*)(ws + (28ull<<20));     // 8 MB
  short* Kb   = (short*)(ws + (36ull<<20));     // 2 MB
  short* VT   = (short*)(ws + (38ull<<20));     // 2 MB
  short* VTs  = (short*)(ws + (40ull<<20));     // 2 MB
  short* attnb= (short*)(ws + (42ull<<20));     // 8 MB
  float* out  = (float*)d_out;

  // pre-pass (hs cast + Wq/Wk/Wv transposes; Wo transpose rides in k_gemm_qkv)
  k_prep<<<dim3(10240), 256, 0, stream>>>(hs, hsb, Wq, WqT, Wk, WkT, Wv, WvT);

  // QKV GEMM (2-buf, 64 KB, swizzled LDS) + fused epilogues + Wo-transpose rider
  k_gemm_qkv<<<dim3(28, 16), 512, 0, stream>>>(hsb, WqT, WkT, WvT, cosT, sinT, nm,
                                               Wo, WoT, Qb, Kb, VT, VTs);

  k_attn3<<<dim3((S_LEN/16)*NH), 64, 0, stream>>>(Qb, Kb, VT, VTs, nm, attnb);

  // Wo GEMM (3-buf counted-vmcnt pipeline, swizzled LDS, 96 KB — 1 block/CU)
  k_gemm<<<dim3(NHD/128, S_LEN/128), 512, 0, stream>>>(attnb, WoT, out, HIDDEN);
}

// Round 15
// 109.206 us; speedup vs baseline: 1.1202x; 1.1200x over previous
//
#include <hip/hip_runtime.h>
#include <hip/hip_bf16.h>
#include <stdint.h>

#define S_LEN  2048
#define HIDDEN 2048
#define NH     32
#define NKVH   8
#define HD     64
#define NHD    (NH*HD)    // 2048
#define KVD    (NKVH*HD)  // 512

typedef __attribute__((ext_vector_type(8))) short  short8;
typedef __attribute__((ext_vector_type(4))) short  short4v;
typedef __attribute__((ext_vector_type(4))) float  f32x4;
typedef __attribute__((ext_vector_type(4))) float  float4v;
typedef __attribute__((ext_vector_type(8))) __bf16 bf16x8;

// counted waits + barriers with memory clobber (rule #18 analog).
#define WAITVM8()  asm volatile("s_waitcnt vmcnt(8)" ::: "memory")
#define WAITVM4()  asm volatile("s_waitcnt vmcnt(4)" ::: "memory")
#define WAITVM0()  asm volatile("s_waitcnt vmcnt(0)" ::: "memory")
#define ABARRIER() asm volatile("s_barrier" ::: "memory")

__device__ __forceinline__ short f2bf(float x){
  uint32_t u = __builtin_bit_cast(uint32_t, x);
  u += 0x7fffu + ((u >> 16) & 1u);   // RNE; inputs are finite
  return (short)(u >> 16);
}

__device__ __forceinline__ f32x4 mfma_bf16(short8 a, short8 b, f32x4 c){
  return __builtin_amdgcn_mfma_f32_16x16x32_bf16(
      __builtin_bit_cast(bf16x8, a), __builtin_bit_cast(bf16x8, b), c, 0, 0, 0);
}

// async global->LDS, 16B per lane; LDS dest = wave-uniform base + lane*16
__device__ __forceinline__ void gload16(const short* g, short* l){
  __builtin_amdgcn_global_load_lds(
      (const __attribute__((address_space(1))) void*)g,
      (__attribute__((address_space(3))) void*)l, 16, 0, 0);
}

// ======== pre-pass: hs f32->bf16 + transpose Wq/Wk/Wv (Wo rides in k_gemm_qkv)
__global__ __launch_bounds__(256) void k_prep(const float* __restrict__ hs,
                                              short* __restrict__ hsb,
                                              const float* __restrict__ Wq, short* __restrict__ WqT,
                                              const float* __restrict__ Wk, short* __restrict__ WkT,
                                              const float* __restrict__ Wv, short* __restrict__ WvT){
  int bid = blockIdx.x;
  if (bid < 4096){
    int i = bid*256 + threadIdx.x;
    float4v v = ((const float4v* __restrict__)hs)[i];
    short4v o;
#pragma unroll
    for (int j=0;j<4;j++) o[j] = f2bf(v[j]);
    ((short4v* __restrict__)hsb)[i] = o;
    return;
  }
  bid -= 4096;
  const float* W; short* WT; int R, C, GX;
  if (bid < 4096)      { W = Wq; WT = WqT; R = HIDDEN; C = NHD; GX = 64; }
  else if (bid < 5120) { bid -= 4096; W = Wk; WT = WkT; R = HIDDEN; C = KVD; GX = 16; }
  else                 { bid -= 5120; W = Wv; WT = WvT; R = HIDDEN; C = KVD; GX = 16; }
  const int bx = bid % GX, by = bid / GX;
  __shared__ float tile[32][33];
  const int x = threadIdx.x & 31, y0 = threadIdx.x >> 5;
  const int c0 = bx*32, r0 = by*32;
#pragma unroll
  for (int yy=y0; yy<32; yy+=8) tile[yy][x] = W[(size_t)(r0+yy)*C + c0 + x];
  __syncthreads();
#pragma unroll
  for (int yy=y0; yy<32; yy+=8) WT[(size_t)(c0+yy)*R + r0 + x] = f2bf(tile[x][yy]);
}

// ==== 2-group in-block split-K GEMM cores (r14 layout; swizzle kept, neutral) ==
struct GemmIdx {
  int wid, r, g, wr, wc, kg, gtid, srow, c8, sx;
};
__device__ __forceinline__ GemmIdx gemm_idx(){
  GemmIdx ix;
  int tid = threadIdx.x, lane = tid&63;
  ix.kg = tid>>8; ix.gtid = tid&255;
  ix.wid = (tid>>6)&3; ix.r = lane&15; ix.g = lane>>4;
  ix.wr = ix.wid>>1; ix.wc = ix.wid&1;
  const int gt = ix.gtid;
  const int row0 = ((gt>>2) ^ (gt>>4)) & 1;
  ix.srow = (((gt>>3)<<1) | row0);
  ix.c8   = ((gt ^ (gt>>2) ^ (gt>>4)) & 1) | ((((gt>>1) ^ (gt>>3)) & 1) << 1);
  ix.sx   = (ix.r & 7) << 3;
  return ix;
}

__device__ __forceinline__ void compute128(const short* As, const short* Bs,
                                           f32x4 acc[4][4], const GemmIdx& ix){
  short8 af[4], bf[4];
#pragma unroll
  for (int m=0;m<4;m++)
    af[m] = *(const short8*)&As[((ix.wr*64 + m*16 + ix.r)*32 + ix.g*8) ^ ix.sx];
#pragma unroll
  for (int n=0;n<4;n++)
    bf[n] = *(const short8*)&Bs[((ix.wc*64 + n*16 + ix.r)*32 + ix.g*8) ^ ix.sx];
#pragma unroll
  for (int m=0;m<4;m++)
#pragma unroll
    for (int n=0;n<4;n++) acc[m][n] = mfma_bf16(af[m], bf[n], acc[m][n]);
}

__device__ __forceinline__ void red_groups(short* LDS, f32x4 acc[4][4], const GemmIdx& ix){
  __syncthreads();
  float* red = (float*)LDS;
  if (ix.kg){
#pragma unroll
    for (int m=0;m<4;m++)
#pragma unroll
      for (int n=0;n<4;n++)
#pragma unroll
        for (int j=0;j<4;j++)
          red[ix.wid*4096 + (m*16 + ix.g*4 + j)*64 + n*16 + ix.r] = acc[m][n][j];
  }
  __syncthreads();
  if (!ix.kg){
#pragma unroll
    for (int m=0;m<4;m++)
#pragma unroll
      for (int n=0;n<4;n++)
#pragma unroll
        for (int j=0;j<4;j++)
          acc[m][n][j] += red[ix.wid*4096 + (m*16 + ix.g*4 + j)*64 + n*16 + ix.r];
  }
}

// 2-buffer core (64 KB total), plain __syncthreads pipeline (r9-proven config).
template<int NKT>
__device__ __forceinline__ void gemm_core2(const short* __restrict__ A,
                                           const short* __restrict__ BT,
                                           int bm, int bn, short* LDS,
                                           f32x4 acc[4][4], const GemmIdx& ix){
  const int K = HIDDEN;
  const short* gA = A  + (size_t)(bm*128 + ix.srow)*K + ix.kg*(NKT*32) + ix.c8*8;
  const short* gB = BT + (size_t)(bn*128 + ix.srow)*K + ix.kg*(NKT*32) + ix.c8*8;
  short* L = LDS + ix.kg*16384;            // 2 bufs * 8192 shorts
  const int w = ix.gtid>>6;

#pragma unroll
  for (int m=0;m<4;m++)
#pragma unroll
    for (int n=0;n<4;n++) acc[m][n] = (f32x4){0.f,0.f,0.f,0.f};

  auto STAGE = [&](int buf, int kt){
    short* As_ = L + buf*8192;             // Bs_ = As_ + 4096
    gload16(gA + kt*32,                As_ + w*512);
    gload16(gA + (size_t)64*K + kt*32, As_ + 2048 + w*512);
    gload16(gB + kt*32,                As_ + 4096 + w*512);
    gload16(gB + (size_t)64*K + kt*32, As_ + 6144 + w*512);
  };

  STAGE(0, 0);
  __syncthreads();                         // buf0 ready
  for (int u=0; u<NKT/2; ++u){
    const int t = 2*u;
    if (t+1 < NKT) STAGE(1, t+1);          // in flight under compute
    compute128(L, L + 4096, acc, ix);
    __syncthreads();                       // buf1 landed; buf0 free
    if (t+2 < NKT) STAGE(0, t+2);
    compute128(L + 8192, L + 12288, acc, ix);
    __syncthreads();
  }
  red_groups(LDS, acc, ix);
}

// 3-buffer core (96 KB): stage-ahead-2, vmcnt(8) — for 1-block/CU kernels (Wo).
template<int NKT>
__device__ __forceinline__ void gemm_core3(const short* __restrict__ A,
                                           const short* __restrict__ BT,
                                           int bm, int bn, short* LDS,
                                           f32x4 acc[4][4], const GemmIdx& ix){
  const int K = HIDDEN;
  const short* gA = A  + (size_t)(bm*128 + ix.srow)*K + ix.kg*(NKT*32) + ix.c8*8;
  const short* gB = BT + (size_t)(bn*128 + ix.srow)*K + ix.kg*(NKT*32) + ix.c8*8;
  short* L = LDS + ix.kg*24576;            // 3 bufs * 8192 shorts
  const int w = ix.gtid>>6;

#pragma unroll
  for (int m=0;m<4;m++)
#pragma unroll
    for (int n=0;n<4;n++) acc[m][n] = (f32x4){0.f,0.f,0.f,0.f};

  auto STAGE = [&](int buf, int kt){
    short* As_ = L + buf*8192;
    gload16(gA + kt*32,                As_ + w*512);
    gload16(gA + (size_t)64*K + kt*32, As_ + 2048 + w*512);
    gload16(gB + kt*32,                As_ + 4096 + w*512);
    gload16(gB + (size_t)64*K + kt*32, As_ + 6144 + w*512);
  };

  STAGE(0, 0);
  STAGE(1, 1);
  int cur = 0;
  for (int t=0; t<NKT-2; ++t){
    int nxt = cur+2; if (nxt>=3) nxt-=3;
    STAGE(nxt, t+2);                       // in flight across the barriers
    WAITVM8();                             // oldest 4 (buf cur) retired
    ABARRIER();
    compute128(L + cur*8192, L + cur*8192 + 4096, acc, ix);
    ABARRIER();
    cur = (cur==2) ? 0 : cur+1;
  }
  WAITVM4();                               // t = NKT-2
  ABARRIER();
  compute128(L + cur*8192, L + cur*8192 + 4096, acc, ix);
  ABARRIER();
  cur = (cur==2) ? 0 : cur+1;
  WAITVM0();                               // t = NKT-1 (final drain)
  ABARRIER();
  compute128(L + cur*8192, L + cur*8192 + 4096, acc, ix);

  red_groups(LDS, acc, ix);
}

// QKV GEMM, fused epilogues + Wo-transpose rider region (bn in [24,28)).
__global__ __launch_bounds__(512, 4) void k_gemm_qkv(const short* __restrict__ hsb,
                                                     const short* __restrict__ WqT,
                                                     const short* __restrict__ WkT,
                                                     const short* __restrict__ WvT,
                                                     const float* __restrict__ cosT,
                                                     const float* __restrict__ sinT,
                                                     const int* __restrict__ nm,
                                                     const float* __restrict__ Wo,
                                                     short* __restrict__ WoT,
                                                     short* __restrict__ Qb,
                                                     short* __restrict__ Kb,
                                                     short* __restrict__ VT,
                                                     short* __restrict__ VTs){
  __shared__ short LDS[32768];             // 64 KB: 2 groups x 2 bufs x 16 KB
  const int bn = blockIdx.x, bm = blockIdx.y;
  GemmIdx ix = gemm_idx();
  f32x4 acc[4][4];

  if (bn < 16){
    gemm_core2<32>(hsb, WqT + (size_t)bn*128*HIDDEN, bm, 0, LDS, acc, ix);
    if (ix.kg) return;
    const int h2 = bn*2 + ix.wc;
#pragma unroll
    for (int m=0;m<4;m++)
#pragma unroll
      for (int j=0;j<4;j++){
        const int s = bm*128 + ix.wr*64 + m*16 + ix.g*4 + j;
        const float* cr = cosT + s*64;
        const float* sr = sinT + s*64;
#pragma unroll
        for (int n=0;n<2;n++){
          const int d = n*16 + ix.r;
          float x1 = acc[m][n][j], x2 = acc[m][n+2][j];
          Qb[(size_t)s*NHD + h2*64 + d]      = f2bf((x1*cr[d]    - x2*sr[d])   *0.125f);
          Qb[(size_t)s*NHD + h2*64 + d + 32] = f2bf((x2*cr[d+32] + x1*sr[d+32])*0.125f);
        }
      }
  } else if (bn < 20){
    gemm_core2<32>(hsb, WkT + (size_t)(bn-16)*128*HIDDEN, bm, 0, LDS, acc, ix);
    if (ix.kg) return;
    const int h2 = (bn-16)*2 + ix.wc;
#pragma unroll
    for (int m=0;m<4;m++)
#pragma unroll
      for (int j=0;j<4;j++){
        const int s = bm*128 + ix.wr*64 + m*16 + ix.g*4 + j;
        const float* cr = cosT + s*64;
        const float* sr = sinT + s*64;
#pragma unroll
        for (int n=0;n<2;n++){
          const int d = n*16 + ix.r;
          float x1 = acc[m][n][j], x2 = acc[m][n+2][j];
          Kb[(size_t)s*KVD + h2*64 + d]      = f2bf(x1*cr[d]    - x2*sr[d]);
          Kb[(size_t)s*KVD + h2*64 + d + 32] = f2bf(x2*cr[d+32] + x1*sr[d+32]);
        }
      }
  } else if (bn < 24){
    gemm_core2<32>(hsb, WvT + (size_t)(bn-20)*128*HIDDEN, bm, 0, LDS, acc, ix);
    // V epilogue via LDS: Vt[128 d][136-stride s] bf16, then coalesced stores.
    const int bs  = nm[0] + 1;                 // power of 2 assumed (nm=3 -> 4)
    const int lbs = 31 - __clz(bs);
    const int d0  = (bn-20)*128;
    const int s0  = bm*128;
    short* Vt = LDS;
    __syncthreads();                           // reduce reads complete
    if (!ix.kg){
#pragma unroll
      for (int n=0;n<4;n++){
        const int dr = ix.wc*64 + n*16 + ix.r;
#pragma unroll
        for (int m=0;m<4;m++){
          const int sc_ = ix.wr*64 + m*16 + ix.g*4;
          short4v o;
#pragma unroll
          for (int j=0;j<4;j++) o[j] = f2bf(acc[m][n][j]);
          *(short4v*)&Vt[dr*136 + sc_] = o;
        }
      }
    }
    __syncthreads();
    const int tid = threadIdx.x;
#pragma unroll
    for (int it=0; it<4; ++it){
      const int row = tid>>2, c8 = (tid&3)*32 + it*8;
      *(short8*)&VT[(size_t)(d0+row)*S_LEN + s0 + c8] = *(short8*)&Vt[row*136 + c8];
    }
    const int cnt = 128 >> lbs;
    for (int e = tid; e < 128*cnt; e += 512){
      const int row = e >> (7 - lbs), c = e & (cnt - 1);
      VTs[(size_t)(d0+row)*S_LEN + (s0>>lbs) + c] = Vt[row*136 + (c<<lbs)];
    }
  } else {
    // Wo transpose rider
    const int bnt = bn - 24;
    float* tf = (float*)LDS;                   // 2 x 32 x 33 floats
    const int tid = threadIdx.x;
    const int half = tid >> 8;
    const int x = tid & 31, y0 = (tid >> 5) & 7;
    const int c0base = bnt*512, r0base = bm*128;
    for (int it=0; it<32; ++it){
      const int t = it*2 + half;               // 0..63
      const int c0 = c0base + (t & 15)*32;
      const int r0 = r0base + (t >> 4)*32;
      __syncthreads();
#pragma unroll
      for (int yy=y0; yy<32; yy+=8)
        tf[half*1056 + yy*33 + x] = Wo[(size_t)(r0+yy)*HIDDEN + c0 + x];
      __syncthreads();
#pragma unroll
      for (int yy=y0; yy<32; yy+=8)
        WoT[(size_t)(c0+yy)*NHD + r0 + x] = f2bf(tf[half*1056 + x*33 + yy]);
    }
  }
}

// Wo GEMM: 2-group split-K, 3-buffer counted-vmcnt pipeline (1 block/CU grid).
__global__ __launch_bounds__(512, 4) void k_gemm(const short* __restrict__ A,
                                                 const short* __restrict__ BT,
                                                 float* __restrict__ C, int Nc){
  __shared__ short LDS[49152];             // 96 KB
  const int bn = blockIdx.x, bm = blockIdx.y;
  GemmIdx ix = gemm_idx();
  f32x4 acc[4][4];
  gemm_core3<32>(A, BT, bm, bn, LDS, acc, ix);
  if (ix.kg) return;
#pragma unroll
  for (int m=0;m<4;m++)
#pragma unroll
    for (int n=0;n<4;n++)
#pragma unroll
      for (int j=0;j<4;j++)
        C[(size_t)(bm*128 + ix.wr*64 + m*16 + ix.g*4 + j)*Nc
          + bn*128 + ix.wc*64 + n*16 + ix.r] = acc[m][n][j];
}

// ======================= attention v6: 32 q-rows per 1-wave block ==============
// 2 m-fragments per wave: each K-tile load feeds 16 QK MFMAs (2x intensity) and
// total tile-iterations halve. Explicit K-prefetch: next tile's fragments are
// issued before the exp/P/PV phase (T14 issue-early). No-max softmax + MFMA-l.

#define BF16_ONE 16256   // 0x3F80

__device__ __forceinline__ void sm_pv2(f32x4 sc[2][4],
                                       f32x4 accl[2],
                                       f32x4 acc[2][4], short* Pw,
                                       const short* Vtile,   // [d][col], stride S_LEN
                                       int r, int g){
  const short8 ones = {BF16_ONE,BF16_ONE,BF16_ONE,BF16_ONE,
                       BF16_ONE,BF16_ONE,BF16_ONE,BF16_ONE};
#pragma unroll
  for (int m=0;m<2;m++)
#pragma unroll
    for (int n=0;n<4;n++)
#pragma unroll
      for (int j=0;j<4;j++)
        Pw[(m*16 + g*4 + j)*72 + n*16 + r] = f2bf(__expf(sc[m][n][j]));

  short8 pf[2][2];
#pragma unroll
  for (int m=0;m<2;m++){
    pf[m][0] = *(short8*)&Pw[(m*16 + r)*72 + g*8];
    pf[m][1] = *(short8*)&Pw[(m*16 + r)*72 + 32 + g*8];
    accl[m] = mfma_bf16(pf[m][0], ones, accl[m]);
    accl[m] = mfma_bf16(pf[m][1], ones, accl[m]);
  }
#pragma unroll
  for (int f=0;f<4;f++){
    short8 vf0 = *(const short8*)(Vtile + (size_t)(f*16 + r)*S_LEN + g*8);
    short8 vf1 = *(const short8*)(Vtile + (size_t)(f*16 + r)*S_LEN + 32 + g*8);
#pragma unroll
    for (int m=0;m<2;m++){
      acc[m][f] = mfma_bf16(pf[m][0], vf0, acc[m][f]);
      acc[m][f] = mfma_bf16(pf[m][1], vf1, acc[m][f]);
    }
  }
}

__global__ __launch_bounds__(64, 3) void k_attn4(const short* __restrict__ Qb,
                                                 const short* __restrict__ Kb,   // [S][KVD]
                                                 const short* __restrict__ VT,   // [KVD][S]
                                                 const short* __restrict__ VTs,  // [KVD][S/bs], stride S
                                                 const int* __restrict__ nm,
                                                 short* __restrict__ Ob){
  const int i  = gridDim.x - 1 - blockIdx.x;   // heavy q-sub-blocks first
  const int qs = i >> 5;                       // 32-row sub-block index, 0..63
  const int h  = i & 31;
  const int hk = h >> 2;
  const int bs = nm[0] + 1;                    // requires bs | 32

  const int lane = threadIdx.x;
  const int r = lane&15, g = lane>>4;

  __shared__ short Pw[32*72];

  const int qlo = qs*32;

  short8 qf[2][2];
#pragma unroll
  for (int m=0;m<2;m++){
    qf[m][0] = *(const short8*)(Qb + (size_t)(qlo + m*16 + r)*NHD + h*HD + g*8);
    qf[m][1] = *(const short8*)(Qb + (size_t)(qlo + m*16 + r)*NHD + h*HD + 32 + g*8);
  }

  f32x4 acc[2][4];
  f32x4 accl[2];
#pragma unroll
  for (int m=0;m<2;m++){
    accl[m] = (f32x4){0.f,0.f,0.f,0.f};
#pragma unroll
    for (int f=0;f<4;f++) acc[m][f] = (f32x4){0.f,0.f,0.f,0.f};
  }

  const short* Kg  = Kb  + hk*HD;
  const short* Vsg = VTs + (size_t)hk*HD*S_LEN;
  const short* Vdg = VT  + (size_t)hk*HD*S_LEN;

  // ---- column pass: keys k = bs*c for c < cmax (all causally allowed) ----
  const int cmax = qlo / bs;                   // exact (bs | 32)
  const int nct = (cmax + 63) >> 6;

  short8 kp[4][2];                             // prefetch buffer (one K tile)
  auto LOADK = [&](int cbase){
#pragma unroll
    for (int n=0;n<4;n++){
      const int key = bs*(cbase + n*16 + r);
      kp[n][0] = *(const short8*)(Kg + (size_t)key*KVD + g*8);
      kp[n][1] = *(const short8*)(Kg + (size_t)key*KVD + 32 + g*8);
    }
  };

  if (nct > 0) LOADK(0);
  for (int ct=0; ct<nct; ++ct){
    const int cbase = ct*64;
    f32x4 sc[2][4];
#pragma unroll
    for (int n=0;n<4;n++){
      const short8 kf0 = kp[n][0], kf1 = kp[n][1];
#pragma unroll
      for (int m=0;m<2;m++){
        f32x4 z = (f32x4){0.f,0.f,0.f,0.f};
        z = mfma_bf16(qf[m][0], kf0, z);
        sc[m][n] = mfma_bf16(qf[m][1], kf1, z);
      }
    }
    if (ct+1 < nct) LOADK(cbase + 64);         // prefetch under exp/P/PV
    if (cmax - cbase < 64){                    // partial last tile only
#pragma unroll
      for (int n=0;n<4;n++){
        if (cbase + n*16 + r >= cmax){
#pragma unroll
          for (int m=0;m<2;m++)
#pragma unroll
            for (int j=0;j<4;j++) sc[m][n][j] = -1e30f;
        }
      }
    }
    sm_pv2(sc, accl, acc, Pw, Vsg + cbase, r, g);
  }

  // ---- diag: the 32 keys [qlo, qlo+32) with the full mask ----
  {
    const short8 ones = {BF16_ONE,BF16_ONE,BF16_ONE,BF16_ONE,
                         BF16_ONE,BF16_ONE,BF16_ONE,BF16_ONE};
    f32x4 sd[2][2];                            // [m][n]
#pragma unroll
    for (int n=0;n<2;n++){
      const int key = qlo + n*16 + r;
      short8 kf0 = *(const short8*)(Kg + (size_t)key*KVD + g*8);
      short8 kf1 = *(const short8*)(Kg + (size_t)key*KVD + 32 + g*8);
#pragma unroll
      for (int m=0;m<2;m++){
        f32x4 z = (f32x4){0.f,0.f,0.f,0.f};
        z = mfma_bf16(qf[m][0], kf0, z);
        sd[m][n] = mfma_bf16(qf[m][1], kf1, z);
      }
    }
    // hoisted div/mod by runtime bs
    int kdn[2]; bool kz[2];
#pragma unroll
    for (int n=0;n<2;n++){
      const int krel = n*16 + r;
      kdn[n] = krel / bs;
      kz[n]  = (krel % bs) == 0;
    }
#pragma unroll
    for (int m=0;m<2;m++)
#pragma unroll
      for (int j=0;j<4;j++){
        const int qrel = m*16 + g*4 + j;
        const int qd = qrel / bs;
#pragma unroll
        for (int n=0;n<2;n++){
          const int krel = n*16 + r;
          bool ok = (krel <= qrel) && (kz[n] || (kdn[n] == qd));
          sd[m][n][j] = ok ? sd[m][n][j] : -1e30f;
        }
      }
    // P rows 0..31, cols 0..31 fully covered by the two fragments
#pragma unroll
    for (int m=0;m<2;m++)
#pragma unroll
      for (int n=0;n<2;n++)
#pragma unroll
        for (int j=0;j<4;j++)
          Pw[(m*16 + g*4 + j)*72 + n*16 + r] = f2bf(__expf(sd[m][n][j]));

    short8 pf[2];
#pragma unroll
    for (int m=0;m<2;m++){
      pf[m] = *(short8*)&Pw[(m*16 + r)*72 + g*8];  // covers k=0..31
      accl[m] = mfma_bf16(pf[m], ones, accl[m]);
    }
#pragma unroll
    for (int f=0;f<4;f++){
      short8 vf = *(const short8*)(Vdg + (size_t)(f*16 + r)*S_LEN + qlo + g*8);
#pragma unroll
      for (int m=0;m<2;m++)
        acc[m][f] = mfma_bf16(pf[m], vf, acc[m][f]);
    }
  }

  // epilogue: O /= l, write bf16 (rows qlo + m*16 + g*4 + j)
#pragma unroll
  for (int m=0;m<2;m++)
#pragma unroll
    for (int j=0;j<4;j++){
      float inv = 1.f / accl[m][j];
      const int q = qlo + m*16 + g*4 + j;
#pragma unroll
      for (int f=0;f<4;f++)
        Ob[(size_t)q*NHD + h*HD + f*16 + r] = f2bf(acc[m][f][j]*inv);
    }
}

// ---------------- launch ----------------
extern "C" void kernel_launch(void* const* d_in, const int* in_sizes, int n_in,
                              void* d_out, int out_size, void* d_ws, size_t ws_size,
                              hipStream_t stream){
  const float* hs   = (const float*)d_in[0];
  const float* cosT = (const float*)d_in[1];
  const float* sinT = (const float*)d_in[2];
  const float* Wq   = (const float*)d_in[3];
  const float* Wk   = (const float*)d_in[4];
  const float* Wv   = (const float*)d_in[5];
  const float* Wo   = (const float*)d_in[6];
  const int*   nm   = (const int*)d_in[7];

  char* ws = (char*)d_ws;
  short* hsb  = (short*)(ws);                   // 8 MB
  short* WqT  = (short*)(ws + (8ull<<20));      // 8 MB
  short* WkT  = (short*)(ws + (16ull<<20));     // 2 MB
  short* WvT  = (short*)(ws + (18ull<<20));     // 2 MB
  short* WoT  = (short*)(ws + (20ull<<20));     // 8 MB
  short* Qb   = (short*)(ws + (28ull<<20));     // 8 MB
  short* Kb   = (short*)(ws + (36ull<<20));     // 2 MB
  short* VT   = (short*)(ws + (38ull<<20));     // 2 MB
  short* VTs  = (short*)(ws + (40ull<<20));     // 2 MB
  short* attnb= (short*)(ws + (42ull<<20));     // 8 MB
  float* out  = (float*)d_out;

  // pre-pass (hs cast + Wq/Wk/Wv transposes; Wo transpose rides in k_gemm_qkv)
  k_prep<<<dim3(10240), 256, 0, stream>>>(hs, hsb, Wq, WqT, Wk, WkT, Wv, WvT);

  // QKV GEMM (2-buf, 64 KB) + fused epilogues + Wo-transpose rider
  k_gemm_qkv<<<dim3(28, 16), 512, 0, stream>>>(hsb, WqT, WkT, WvT, cosT, sinT, nm,
                                               Wo, WoT, Qb, Kb, VT, VTs);

  // attention v6: 32 q-rows per 1-wave block + K-prefetch
  k_attn4<<<dim3((S_LEN/32)*NH), 64, 0, stream>>>(Qb, Kb, VT, VTs, nm, attnb);

  // Wo GEMM (3-buf counted-vmcnt pipeline, 96 KB — 1 block/CU)
  k_gemm<<<dim3(NHD/128, S_LEN/128), 512, 0, stream>>>(attnb, WoT, out, HIDDEN);
}